// Round 15
// baseline (210.254 us; speedup 1.0000x reference)
//
#include <hip/hip_runtime.h>
#include <stdint.h>

#define B_ 8
#define C_ 256
#define H_ 96
#define W_ 160
#define ND 9
#define NDISP 81
#define CK 2                   // channels per chunk
#define NCHUNK (C_ / CK)       // 128
#define TX 8
#define NXG 20
#define NTHR 64                // ONE wave per block; no barriers
#define NCOMP 60               // 3 dyl * 20 xg
// Per-chunk LDS layout: 8 row-slots of 688 B (43*16: R8 invariant).
//   row R: ch = R>>2, r = R&3; r==0 -> in1 row y (160 f @ +0);
//   r=1..3 -> in2 row y+dyg*3+(r-1)-4, x in [-4,164) (168 f @ +0).
#define ROW_B 688
#define CH_B  2752             // 4 * 688
#define CHUNK_B 5504           // 2 channels
#define BUF_B 6144             // 6 x 1024B DMA slots; %512==0
#define NBUF 2                 // 12288 B total LDS
#define HW (H_ * W_)
#define CHSTEP (CK * HW)

typedef const __attribute__((address_space(1))) void GV;
typedef __attribute__((address_space(3))) void LV;
#define DMA16(g, l) __builtin_amdgcn_global_load_lds((GV*)(g), (LV*)(l), 16, 0, 0)

// Linear layout (no swizzle: conflict counter proven layout-invariant,
// dominated by DMA-write interference). Clamped cells = masked garbage.
__device__ __forceinline__ const float* decode_src(int O, int b, int y,
        int dyg, const float* in1, const float* in2)
{
    if (O >= CHUNK_B) return in1;          // slot tail dummy (never read)
    const int R  = O / ROW_B;
    const int fb = O - R * ROW_B;          // 16-aligned
    const int ch = R >> 2;
    const int r  = R & 3;
    if (r == 0) {                          // in1 row y
        const int x = (fb < 640) ? (fb >> 2) : 0;    // reads end <= 640 ✓
        return in1 + ((size_t)(b * C_ + ch) * H_ + y) * W_ + x;
    }
    int row = y + dyg * 3 + (r - 1) - 4;
    row = row < 0 ? 0 : (row >= H_ ? H_ - 1 : row);  // clamp; masked later
    int x = (fb < 672) ? ((fb >> 2) - 4) : 0;        // reads end <= 672 ✓
    x = x < 0 ? 0 : (x > W_ - 4 ? W_ - 4 : x);       // clamp; masked later
    return in2 + ((size_t)(b * C_ + ch) * H_ + row) * W_ + x;
}

__global__ __launch_bounds__(NTHR, 2) void corr_rp_kernel(
    const float* __restrict__ in1,
    const float* __restrict__ in2,
    float* __restrict__ out)
{
    __shared__ float lds[NBUF * BUF_B / 4];   // 12288 B, never zero-inited

    const int tid = threadIdx.x;
    const int b   = blockIdx.x & 7;       // XCD swizzle: batch pinned to XCD
    const int idx = blockIdx.x >> 3;      // 0..287
    const int y   = idx / 3;
    const int dyg = idx % 3;              // dy = dyg*3 + dyl

    // ---- per-lane DMA sources: 6 slots
    const float* g0 = decode_src(0 * 1024 + tid * 16, b, y, dyg, in1, in2);
    const float* g1 = decode_src(1 * 1024 + tid * 16, b, y, dyg, in1, in2);
    const float* g2 = decode_src(2 * 1024 + tid * 16, b, y, dyg, in1, in2);
    const float* g3 = decode_src(3 * 1024 + tid * 16, b, y, dyg, in1, in2);
    const float* g4 = decode_src(4 * 1024 + tid * 16, b, y, dyg, in1, in2);
    const float* g5 = decode_src(5 * 1024 + tid * 16, b, y, dyg, in1, in2);

    // ---- compute coords; lanes 60-63 clamp onto 0-3 (broadcast, not stored)
    const bool isComp = (tid < NCOMP);
    const int  dyl = isComp ? (tid / NXG) : 0;
    const int  xg  = isComp ? (tid % NXG) : (tid - NCOMP);
    const int  x0  = TX * xg;
    const int  dy  = dyg * 3 + dyl;
    const bool rowOk = (y + dy - 4 >= 0) && (y + dy - 4 < H_);
    const bool mzW0 = (xg == 0);          // w0 = x [-4,0): zero-pad
    const bool mzW3 = (xg == NXG - 1);    // w3 = x [160,164)

    // ---- read offsets (bytes, buffer-local, linear)
    const int aof0 = 32 * xg;                          // ch0 in1 (+0,+16)
    const int aof1 = CH_B + 32 * xg;                   // ch1 in1
    const int wof0 = (1 + dyl) * ROW_B + 32 * xg;      // ch0 in2 (+0..+48)
    const int wof1 = CH_B + (1 + dyl) * ROW_B + 32 * xg;

    float acc[ND][TX];
    #pragma unroll
    for (int dx = 0; dx < ND; ++dx)
        #pragma unroll
        for (int j = 0; j < TX; ++j) acc[dx][j] = 0.f;

    // named staging registers, two sets (rule #20: no arrays, no structs)
    float4 Aa00, Aa01, Aa10, Aa11, Aw00, Aw01, Aw02, Aw03, Aw10, Aw11, Aw12, Aw13;
    float4 Ba00, Ba01, Ba10, Ba11, Bw00, Bw01, Bw02, Bw03, Bw10, Bw11, Bw12, Bw13;

    #define ISSUE(BUFI) do {                                                  \
        char* lb = (char*)lds + (BUFI) * BUF_B;                               \
        DMA16(g0, lb);            DMA16(g1, lb + 1024);                       \
        DMA16(g2, lb + 2048);     DMA16(g3, lb + 3072);                       \
        DMA16(g4, lb + 4096);     DMA16(g5, lb + 5120);                       \
        g0 += CHSTEP; g1 += CHSTEP; g2 += CHSTEP;                             \
        g3 += CHSTEP; g4 += CHSTEP; g5 += CHSTEP;                             \
    } while (0);

    #define READS(BUFI, S) {                                                  \
        const char* bb = (const char*)lds + (BUFI) * BUF_B;                   \
        S##a00 = *(const float4*)(bb + aof0);                                 \
        S##a01 = *(const float4*)(bb + aof0 + 16);                            \
        S##a10 = *(const float4*)(bb + aof1);                                 \
        S##a11 = *(const float4*)(bb + aof1 + 16);                            \
        S##w00 = *(const float4*)(bb + wof0);                                 \
        S##w01 = *(const float4*)(bb + wof0 + 16);                            \
        S##w02 = *(const float4*)(bb + wof0 + 32);                            \
        S##w03 = *(const float4*)(bb + wof0 + 48);                            \
        S##w10 = *(const float4*)(bb + wof1);                                 \
        S##w11 = *(const float4*)(bb + wof1 + 16);                            \
        S##w12 = *(const float4*)(bb + wof1 + 32);                            \
        S##w13 = *(const float4*)(bb + wof1 + 48);                            \
    }

    #define FMACH(A0, A1, W0, W1, W2, W3) {                                   \
        float4 w0v = (W0), w3v = (W3);                                        \
        if (mzW0) w0v = make_float4(0.f, 0.f, 0.f, 0.f);                      \
        if (mzW3) w3v = make_float4(0.f, 0.f, 0.f, 0.f);                      \
        float a[8]  = {(A0).x, (A0).y, (A0).z, (A0).w,                        \
                       (A1).x, (A1).y, (A1).z, (A1).w};                       \
        float w[16] = {w0v.x, w0v.y, w0v.z, w0v.w,                            \
                       (W1).x, (W1).y, (W1).z, (W1).w,                        \
                       (W2).x, (W2).y, (W2).z, (W2).w,                        \
                       w3v.x, w3v.y, w3v.z, w3v.w};                           \
        _Pragma("unroll")                                                     \
        for (int dx = 0; dx < ND; ++dx) {                                     \
            _Pragma("unroll")                                                 \
            for (int j = 0; j < TX; ++j)                                      \
                acc[dx][j] += a[j] * w[dx + j];                               \
        }                                                                     \
    }

    #define FMAS(S)                                                           \
        FMACH(S##a00, S##a01, S##w00, S##w01, S##w02, S##w03)                 \
        FMACH(S##a10, S##a11, S##w10, S##w11, S##w12, S##w13)

    // body kc (buf = kc&1):
    //  lgkmcnt(0): regCUR's reads (issued body kc-1) done; buf kc&1 dead.
    //  ISSUE kc+2 into buf kc&1.  vmcnt(6): chunk kc+1 landed (kc+2 in
    //  flight).  Issue 12 ds_reads of kc+1 -> regNXT.  FMA regCUR with NO
    //  waits, overlapping the in-flight reads.
    #define BODY(BUFI, WN, DOISS, DORD, CUR, NXT)                             \
        asm volatile("s_waitcnt lgkmcnt(0)" ::: "memory");                    \
        __builtin_amdgcn_sched_barrier(0);                                    \
        if (DOISS) { ISSUE(BUFI) }                                            \
        asm volatile("s_waitcnt vmcnt(" WN ")" ::: "memory");                 \
        __builtin_amdgcn_sched_barrier(0);                                    \
        if (DORD) { READS((BUFI) ^ 1, NXT) }                                  \
        __builtin_amdgcn_sched_barrier(0);                                    \
        FMAS(CUR)

    // ---- prologue: stage chunks 0,1; read chunk 0 -> A
    ISSUE(0)
    ISSUE(1)
    asm volatile("s_waitcnt vmcnt(6)" ::: "memory");   // chunk 0 landed
    READS(0, A)

    // ---- main loop: kc = 0..125
    #pragma unroll 1
    for (int g = 0; g < 63; ++g) {
        BODY(0, "6", true, true, A, B)
        BODY(1, "6", true, true, B, A)
    }
    // ---- tail: kc = 126 (reads 127), kc = 127 (FMA only)
    BODY(0, "0", false, true, A, B)
    asm volatile("s_waitcnt lgkmcnt(0)" ::: "memory");
    FMAS(B)

    #undef BODY
    #undef FMAS
    #undef FMACH
    #undef READS
    #undef ISSUE

    // ---- epilogue: OOB-dy rows output zeros (masked scale; staged clamped
    // garbage is finite real data, so 0-scale is exact)
    if (isComp) {
        const float m = rowOk ? (1.0f / (float)C_) : 0.f;
        float* outp = out + ((size_t)(b * NDISP + dy * ND) * H_ + y) * W_ + x0;
        #pragma unroll
        for (int dx = 0; dx < ND; ++dx) {
            float4 o0 = make_float4(acc[dx][0] * m, acc[dx][1] * m,
                                    acc[dx][2] * m, acc[dx][3] * m);
            float4 o1 = make_float4(acc[dx][4] * m, acc[dx][5] * m,
                                    acc[dx][6] * m, acc[dx][7] * m);
            *(float4*)(outp + dx * HW)     = o0;
            *(float4*)(outp + dx * HW + 4) = o1;
        }
    }
}

extern "C" void kernel_launch(void* const* d_in, const int* in_sizes, int n_in,
                              void* d_out, int out_size, void* d_ws, size_t ws_size,
                              hipStream_t stream) {
    const float* in1 = (const float*)d_in[0];
    const float* in2 = (const float*)d_in[1];
    float* out = (float*)d_out;

    const int grid = B_ * H_ * 3;   // 2304 single-wave blocks
    corr_rp_kernel<<<grid, NTHR, 0, stream>>>(in1, in2, out);
}

// Round 16
// 142.104 us; speedup vs baseline: 1.4796x; 1.4796x over previous
//
#include <hip/hip_runtime.h>
#include <stdint.h>

#define B_ 8
#define C_ 256
#define H_ 96
#define W_ 160
#define ND 9
#define NDISP 81
#define NCHUNK 128             // channel-pairs
#define TX 4
#define NXG 20
#define NTHR 64                // ONE wave per block (R12 geometry)
#define NCOMP 60
// Staged chunk = one channel-PAIR as f16-pair words (c lo, c+1 hi):
//   in1: 80 words (x [80h, 80h+80))            @ 0
//   in2 r=0..2: 88 words (x [80h-4, 80h+84))   @ 320 + r*352
#define NSEG 86                // 16B segments: 20 in1 + 3*22 in2
#define IN1_B 320
#define ROW_B 352
#define DATA_B 1376
#define BUF_B 2048             // data + pad (dummy-slot writes land in pad)
#define HW (H_ * W_)
#define CHSTEP (2 * HW)        // channel-pair step

typedef __attribute__((ext_vector_type(2))) _Float16 half2v;

__device__ __forceinline__ unsigned pk(float lo, float hi) {
    return __builtin_bit_cast(unsigned, __builtin_amdgcn_cvt_pkrtz(lo, hi));
}

__device__ __forceinline__ float dot2acc(unsigned a, unsigned w, float acc) {
#if __has_builtin(__builtin_amdgcn_fdot2)
    return __builtin_amdgcn_fdot2(__builtin_bit_cast(half2v, a),
                                  __builtin_bit_cast(half2v, w), acc, false);
#else
    half2v av = __builtin_bit_cast(half2v, a);
    half2v wv = __builtin_bit_cast(half2v, w);
    return acc + (float)av.x * (float)wv.x + (float)av.y * (float)wv.y;
#endif
}

// Segment s -> global fp32 source (channel 0 base) + LDS byte offset.
// Clamped cells hold finite garbage, masked at dot2 / store time.
__device__ __forceinline__ const float* seg_src(int s, int b, int y, int dyg,
        int h, const float* in1, const float* in2, int* woff)
{
    if (s >= NSEG) {                       // dummy slot -> pad region
        *woff = DATA_B + (s - NSEG) * 16;
        return in1;
    }
    if (s < 20) {                          // in1 seg: x = 80h + 4s
        *woff = s * 16;
        return in1 + ((size_t)(b * C_) * H_ + y) * W_ + 80 * h + 4 * s;
    }
    const int r  = (s - 20) / 22;          // dyl row
    const int cs = (s - 20) % 22;
    *woff = IN1_B + r * ROW_B + cs * 16;
    int row = y + dyg * 3 + r - 4;
    row = row < 0 ? 0 : (row >= H_ ? H_ - 1 : row);      // clamp; masked later
    int x = 80 * h - 4 + 4 * cs;
    x = x < 0 ? 0 : (x > W_ - 4 ? W_ - 4 : x);           // clamp; masked later
    return in2 + ((size_t)(b * C_) * H_ + row) * W_ + x; // 16B-aligned
}

__global__ __launch_bounds__(NTHR) void corr_f16_kernel(
    const float* __restrict__ in1,
    const float* __restrict__ in2,
    float* __restrict__ out)
{
    __shared__ __align__(16) unsigned lds[2 * BUF_B / 4];   // 4096 B

    const int tid = threadIdx.x;
    const int b   = blockIdx.x & 7;       // XCD swizzle: batch pinned to XCD
    const int idx = blockIdx.x >> 3;      // 0..575
    const int y   = idx / 6;
    const int t6  = idx % 6;
    const int dyg = t6 >> 1;              // dy = dyg*3 + dyl
    const int h   = t6 & 1;               // x half

    // ---- staging slots: seg tid and tid+64
    int off0, off1;
    const float* p0 = seg_src(tid,      b, y, dyg, h, in1, in2, &off0);
    const float* p1 = seg_src(tid + 64, b, y, dyg, h, in1, in2, &off1);

    // ---- compute coords; lanes 60-63 clamp onto 0-3 (junk, never stored)
    const bool isComp = (tid < NCOMP);
    const int  dyl = isComp ? (tid / NXG) : 0;
    const int  xg  = isComp ? (tid % NXG) : (tid - NCOMP);
    const int  x0  = 80 * h + TX * xg;
    const int  dy  = dyg * 3 + dyl;
    const bool rowOk = (y + dy - 4 >= 0) && (y + dy - 4 < H_);
    const bool mzW0 = (h == 0) && (xg == 0);        // pair-words x [-4,0)
    const bool mzW2 = (h == 1) && (xg == NXG - 1);  // pair-words x [160,164)

    const int aof = 16 * xg;                        // in1 words [4xg,4xg+4)
    const int wof = IN1_B + dyl * ROW_B + 16 * xg;  // in2 words [4xg-4,4xg+8)

    float acc[ND][TX];
    #pragma unroll
    for (int dx = 0; dx < ND; ++dx)
        #pragma unroll
        for (int j = 0; j < TX; ++j) acc[dx][j] = 0.f;

    float4 La0, La1, Lb0, Lb1;            // raw fp32 staging (named, rule #20)

    #define LOADS do {                                                        \
        La0 = *(const float4*)(p0);  La1 = *(const float4*)(p0 + HW);         \
        Lb0 = *(const float4*)(p1);  Lb1 = *(const float4*)(p1 + HW);         \
        p0 += CHSTEP; p1 += CHSTEP;                                           \
    } while (0);

    #define CVTWRITE(BUFI) do {                                               \
        char* base = (char*)lds + (BUFI) * BUF_B;                             \
        *(uint4*)(base + off0) = make_uint4(                                  \
            pk(La0.x, La1.x), pk(La0.y, La1.y),                               \
            pk(La0.z, La1.z), pk(La0.w, La1.w));                              \
        *(uint4*)(base + off1) = make_uint4(                                  \
            pk(Lb0.x, Lb1.x), pk(Lb0.y, Lb1.y),                               \
            pk(Lb0.z, Lb1.z), pk(Lb0.w, Lb1.w));                              \
    } while (0);

    #define COMPUTE(BUFI) {                                                   \
        const char* bb = (const char*)lds + (BUFI) * BUF_B;                   \
        uint4 av = *(const uint4*)(bb + aof);                                 \
        uint4 w0 = *(const uint4*)(bb + wof);                                 \
        uint4 w1 = *(const uint4*)(bb + wof + 16);                            \
        uint4 w2 = *(const uint4*)(bb + wof + 32);                            \
        if (mzW0) w0 = make_uint4(0u, 0u, 0u, 0u);                            \
        if (mzW2) w2 = make_uint4(0u, 0u, 0u, 0u);                            \
        unsigned a[4]  = {av.x, av.y, av.z, av.w};                            \
        unsigned w[12] = {w0.x, w0.y, w0.z, w0.w, w1.x, w1.y, w1.z, w1.w,     \
                          w2.x, w2.y, w2.z, w2.w};                            \
        _Pragma("unroll")                                                     \
        for (int dx = 0; dx < ND; ++dx) {                                     \
            _Pragma("unroll")                                                 \
            for (int j = 0; j < TX; ++j)                                      \
                acc[dx][j] = dot2acc(a[j], w[dx + j], acc[dx][j]);            \
        }                                                                     \
    }

    // body kc: COMPUTE buf[kc&1] (written 2 bodies ago, lgkm long-retired);
    // CVTWRITE chunk kc+1 (regs loaded last body; vmcnt auto) into buf^1;
    // issue LOADS for chunk kc+2. Wave-local; compiler tracks all deps.
    #define BODY(BUFI, DOCVT, DOLOAD)                                         \
        COMPUTE(BUFI)                                                         \
        if (DOCVT) { CVTWRITE((BUFI) ^ 1) }                                   \
        if (DOLOAD) { LOADS }

    // ---- prologue: chunk0 -> buf0; chunk1 raw in regs
    LOADS                      // chunk 0
    CVTWRITE(0)
    LOADS                      // chunk 1

    // ---- main loop: kc = 0..125 (loads chunks 2..127)
    #pragma unroll 1
    for (int g = 0; g < 63; ++g) {
        BODY(0, true, true)
        BODY(1, true, true)
    }
    // ---- tail: kc = 126 (writes chunk 127), kc = 127
    BODY(0, true, false)
    BODY(1, false, false)

    #undef BODY
    #undef COMPUTE
    #undef CVTWRITE
    #undef LOADS

    // ---- epilogue: OOB-dy rows output zeros via masked scale
    if (isComp) {
        const float m = rowOk ? (1.0f / (float)C_) : 0.f;
        float* outp = out + ((size_t)(b * NDISP + dy * ND) * H_ + y) * W_ + x0;
        #pragma unroll
        for (int dx = 0; dx < ND; ++dx) {
            float4 o = make_float4(acc[dx][0] * m, acc[dx][1] * m,
                                   acc[dx][2] * m, acc[dx][3] * m);
            *(float4*)(outp + dx * HW) = o;
        }
    }
}

extern "C" void kernel_launch(void* const* d_in, const int* in_sizes, int n_in,
                              void* d_out, int out_size, void* d_ws, size_t ws_size,
                              hipStream_t stream) {
    const float* in1 = (const float*)d_in[0];
    const float* in2 = (const float*)d_in[1];
    float* out = (float*)d_out;

    const int grid = B_ * H_ * 3 * 2;   // 4608 single-wave blocks (R12 grid)
    corr_f16_kernel<<<grid, NTHR, 0, stream>>>(in1, in2, out);
}

// Round 18
// 110.274 us; speedup vs baseline: 1.9067x; 1.2886x over previous
//
#include <hip/hip_runtime.h>
#include <stdint.h>

#define B_ 8
#define C_ 256
#define H_ 96
#define W_ 160
#define ND 9
#define NDISP 81
#define NCHUNK 128             // channel-pairs
#define TX 8
#define NXG 20
#define NTHR 256               // 4 waves
#define NCOMP 180              // 9 dy * 20 xg
// Per-buffer f16-pair layout (bytes): in1 row: 160 words @0 (640 B);
// in2 row r(=dy): 168 words (x in [-4,164)) @ 640 + r*688. 688=43*16 (R8 inv).
#define IN2_OFF 640
#define ROW_B 688
#define BUF_B 6912             // 640 + 9*688 = 6832, padded
#define NBUF 4                 // write-ahead-2 -> ONE barrier per chunk
#define NSEG 418               // uint4 segments/chunk: 40 in1 + 9*42 in2
#define HW (H_ * W_)
#define CHSTEP (2 * HW)        // channel-pair step

typedef __attribute__((ext_vector_type(2))) _Float16 half2v;

__device__ __forceinline__ unsigned pk(float lo, float hi) {
    return __builtin_bit_cast(unsigned, __builtin_amdgcn_cvt_pkrtz(lo, hi));
}
__device__ __forceinline__ float dot2acc(unsigned a, unsigned w, float acc) {
#if __has_builtin(__builtin_amdgcn_fdot2)
    return __builtin_amdgcn_fdot2(__builtin_bit_cast(half2v, a),
                                  __builtin_bit_cast(half2v, w), acc, false);
#else
    half2v av = __builtin_bit_cast(half2v, a);
    half2v wv = __builtin_bit_cast(half2v, w);
    return acc + (float)av.x * (float)wv.x + (float)av.y * (float)wv.y;
#endif
}

// uint4 segment s -> fp32 source (channel-pair base ch=0) + LDS byte offset.
// Clamped cells hold finite garbage, masked at dot2/store time.
__device__ __forceinline__ const float* seg_src(int s, int b, int y,
        const float* in1, const float* in2, int* woff)
{
    if (s < 40) {                          // in1: x = 4s
        *woff = s * 16;
        return in1 + ((size_t)(b * C_) * H_ + y) * W_ + 4 * s;
    }
    const int t = s - 40;
    const int r = t / 42, k = t - r * 42;  // dy row, word-seg
    *woff = IN2_OFF + r * ROW_B + k * 16;
    int row = y + r - 4;
    row = row < 0 ? 0 : (row >= H_ ? H_ - 1 : row);      // clamp; masked later
    int x = 4 * k - 4;
    x = x < 0 ? 0 : (x > W_ - 4 ? W_ - 4 : x);           // clamp; masked later
    return in2 + ((size_t)(b * C_) * H_ + row) * W_ + x; // 16B-aligned
}

__global__ __launch_bounds__(NTHR) void corr_alldy_kernel(
    const float* __restrict__ in1,
    const float* __restrict__ in2,
    float* __restrict__ out)
{
    __shared__ __align__(16) unsigned lds[NBUF * BUF_B / 4];   // 27648 B

    const int tid = threadIdx.x;
    const int b   = blockIdx.x & 7;       // XCD swizzle: batch pinned to XCD
    const int y   = blockIdx.x >> 3;

    // ---- staging slots (2 per thread; slot1 invalid for tid >= 162)
    int w0off, w1off = 0;
    const float* p0 = seg_src(tid, b, y, in1, in2, &w0off);
    const bool v1 = (tid + NTHR) < NSEG;
    const float* p1 = in1;                // safe dummy (advances within in1)
    if (v1) p1 = seg_src(tid + NTHR, b, y, in1, in2, &w1off);

    // ---- compute coords (lanes 0..179): dy-major
    const bool isComp = (tid < NCOMP);
    const int  dy = isComp ? (tid / NXG) : 0;
    const int  xg = isComp ? (tid % NXG) : 0;
    const int  x0 = TX * xg;
    const bool rowOk = (y + dy - 4 >= 0) && (y + dy - 4 < H_);
    const bool mzW0 = (xg == 0);          // words x [-4,0): zero-pad
    const bool mzW3 = (xg == NXG - 1);    // words x [160,164)

    const int aof = 32 * xg;                    // in1 words [8xg, 8xg+8)
    const int wof = IN2_OFF + dy * ROW_B + 32 * xg;  // in2 words [8xg-4,8xg+12)

    float acc[ND][TX];
    #pragma unroll
    for (int dx = 0; dx < ND; ++dx)
        #pragma unroll
        for (int j = 0; j < TX; ++j) acc[dx][j] = 0.f;

    // staging register sets (named float4s, letter-first suffixes: pp-number
    // paste bug in R17 — S##0a swallowed ".x" into one pp-number token)
    float4 SAp0, SAp1, SAq0, SAq1;
    float4 SBp0, SBp1, SBq0, SBq1;

    #define LOADS(S) do {                                                     \
        S##p0 = *(const float4*)(p0);  S##p1 = *(const float4*)(p0 + HW);     \
        S##q0 = *(const float4*)(p1);  S##q1 = *(const float4*)(p1 + HW);     \
        p0 += CHSTEP; p1 += CHSTEP;                                           \
    } while (0);

    #define CVTW(BUFI, S) do {                                                \
        char* base = (char*)lds + (BUFI) * BUF_B;                             \
        *(uint4*)(base + w0off) = make_uint4(                                 \
            pk(S##p0.x, S##p1.x), pk(S##p0.y, S##p1.y),                       \
            pk(S##p0.z, S##p1.z), pk(S##p0.w, S##p1.w));                      \
        if (v1) *(uint4*)(base + w1off) = make_uint4(                         \
            pk(S##q0.x, S##q1.x), pk(S##q0.y, S##q1.y),                       \
            pk(S##q0.z, S##q1.z), pk(S##q0.w, S##q1.w));                      \
    } while (0);

    #define COMPUTE(BUFI)                                                     \
    if (isComp) {                                                             \
        const char* bb = (const char*)lds + (BUFI) * BUF_B;                   \
        uint4 A0 = *(const uint4*)(bb + aof);                                 \
        uint4 A1 = *(const uint4*)(bb + aof + 16);                            \
        uint4 W0 = *(const uint4*)(bb + wof);                                 \
        uint4 W1 = *(const uint4*)(bb + wof + 16);                            \
        uint4 W2 = *(const uint4*)(bb + wof + 32);                            \
        uint4 W3 = *(const uint4*)(bb + wof + 48);                            \
        if (mzW0) W0 = make_uint4(0u, 0u, 0u, 0u);                            \
        if (mzW3) W3 = make_uint4(0u, 0u, 0u, 0u);                            \
        unsigned a[8]  = {A0.x, A0.y, A0.z, A0.w, A1.x, A1.y, A1.z, A1.w};    \
        unsigned w[16] = {W0.x, W0.y, W0.z, W0.w, W1.x, W1.y, W1.z, W1.w,     \
                          W2.x, W2.y, W2.z, W2.w, W3.x, W3.y, W3.z, W3.w};    \
        _Pragma("unroll")                                                     \
        for (int dx = 0; dx < ND; ++dx) {                                     \
            _Pragma("unroll")                                                 \
            for (int j = 0; j < TX; ++j)                                      \
                acc[dx][j] = dot2acc(a[j], w[dx + j], acc[dx][j]);            \
        }                                                                     \
    }

    // body kc (buf kc&3): CVTW chunk kc+2 into buf (kc+2)&3 (regs loaded
    // last body; compiler-inserted vmcnt has ~1 body slack); LOADS kc+3
    // early (covered by compute before the barrier drain); COMPUTE kc
    // (written 2 bodies + 2 barriers ago); ONE __syncthreads per chunk.
    #define BODY(KM4, SWR, SLD, DOW, DOL)                                     \
        if (DOW) { CVTW(((KM4) + 2) & 3, SWR) }                               \
        if (DOL) { LOADS(SLD) }                                               \
        COMPUTE(KM4)                                                          \
        __syncthreads();

    // ---- prologue: c0->buf0, c1->buf1 (via SA), c2 -> SB regs
    LOADS(SA)          // c0
    CVTW(0, SA)
    LOADS(SA)          // c1
    CVTW(1, SA)
    LOADS(SB)          // c2
    __syncthreads();

    // ---- main loop: kc = 0..123 (even kc: write from SB, load -> SA)
    #pragma unroll 1
    for (int g = 0; g < 31; ++g) {
        BODY(0, SB, SA, true, true)
        BODY(1, SA, SB, true, true)
        BODY(2, SB, SA, true, true)
        BODY(3, SA, SB, true, true)
    }
    // ---- tail: kc = 124..127
    BODY(0, SB, SA, true, true)    // writes c126, loads c127 -> SA
    BODY(1, SA, SB, true, false)   // writes c127
    BODY(2, SA, SA, false, false)
    BODY(3, SA, SA, false, false)

    #undef BODY
    #undef COMPUTE
    #undef CVTW
    #undef LOADS

    // ---- epilogue: OOB-dy rows output zeros via masked scale
    if (isComp) {
        const float m = rowOk ? (1.0f / (float)C_) : 0.f;
        float* outp = out + ((size_t)(b * NDISP + dy * ND) * H_ + y) * W_ + x0;
        #pragma unroll
        for (int dx = 0; dx < ND; ++dx) {
            float4 o0 = make_float4(acc[dx][0] * m, acc[dx][1] * m,
                                    acc[dx][2] * m, acc[dx][3] * m);
            float4 o1 = make_float4(acc[dx][4] * m, acc[dx][5] * m,
                                    acc[dx][6] * m, acc[dx][7] * m);
            *(float4*)(outp + dx * HW)     = o0;
            *(float4*)(outp + dx * HW + 4) = o1;
        }
    }
}

extern "C" void kernel_launch(void* const* d_in, const int* in_sizes, int n_in,
                              void* d_out, int out_size, void* d_ws, size_t ws_size,
                              hipStream_t stream) {
    const float* in1 = (const float*)d_in[0];
    const float* in2 = (const float*)d_in[1];
    float* out = (float*)d_out;

    const int grid = B_ * H_;   // 768 blocks (b, y); all 9 dy inside block
    corr_alldy_kernel<<<grid, NTHR, 0, stream>>>(in1, in2, out);
}

// Round 19
// 109.886 us; speedup vs baseline: 1.9134x; 1.0035x over previous
//
#include <hip/hip_runtime.h>
#include <stdint.h>

#define B_ 8
#define C_ 256
#define H_ 96
#define W_ 160
#define ND 9
#define NDISP 81
#define NCHUNK 128             // channel-pairs
#define TX 4
#define NXG 20                 // x-groups per half (80 = 20*4)
#define NTHR 256               // 4 waves
#define NCOMP 180              // 9 dy * 20 xg
// Per-buffer f16-pair layout (bytes): in1: 80 words @0 (320 B);
// in2 row r(=dy): 88 words (x in [80h-4, 80h+84)) @ 320 + r*352.
#define IN2_OFF 320
#define ROW_B 352              // 22*16
#define BUF_B 3584             // 320 + 9*352 = 3488, padded to 16-mult
#define NBUF 4                 // write-ahead-2 -> ONE barrier per chunk
#define NSEG 218               // uint4 segments/chunk: 20 in1 + 9*22 in2
#define HW (H_ * W_)
#define CHSTEP (2 * HW)        // channel-pair step

typedef __attribute__((ext_vector_type(2))) _Float16 half2v;

__device__ __forceinline__ unsigned pk(float lo, float hi) {
    return __builtin_bit_cast(unsigned, __builtin_amdgcn_cvt_pkrtz(lo, hi));
}
__device__ __forceinline__ float dot2acc(unsigned a, unsigned w, float acc) {
#if __has_builtin(__builtin_amdgcn_fdot2)
    return __builtin_amdgcn_fdot2(__builtin_bit_cast(half2v, a),
                                  __builtin_bit_cast(half2v, w), acc, false);
#else
    half2v av = __builtin_bit_cast(half2v, a);
    half2v wv = __builtin_bit_cast(half2v, w);
    return acc + (float)av.x * (float)wv.x + (float)av.y * (float)wv.y;
#endif
}

// uint4 segment s -> fp32 source (even channel base) + LDS byte offset.
// Clamped cells hold finite garbage, masked at dot2/store time.
__device__ __forceinline__ const float* seg_src(int s, int b, int y, int h,
        const float* in1, const float* in2, int* woff)
{
    if (s < 20) {                          // in1: x = 80h + 4s (all real)
        *woff = s * 16;
        return in1 + ((size_t)(b * C_) * H_ + y) * W_ + 80 * h + 4 * s;
    }
    const int t = s - 20;
    const int r = t / 22, k = t - r * 22;  // dy row, word-seg
    *woff = IN2_OFF + r * ROW_B + k * 16;
    int row = y + r - 4;
    row = row < 0 ? 0 : (row >= H_ ? H_ - 1 : row);      // clamp; masked later
    int x = 80 * h - 4 + 4 * k;
    x = x < 0 ? 0 : (x > W_ - 4 ? W_ - 4 : x);           // clamp; masked later
    return in2 + ((size_t)(b * C_) * H_ + row) * W_ + x; // 16B-aligned
}

__global__ __launch_bounds__(NTHR) void corr_hx16_kernel(
    const float* __restrict__ in1,
    const float* __restrict__ in2,
    float* __restrict__ out)
{
    __shared__ __align__(16) unsigned lds[NBUF * BUF_B / 4];   // 14336 B

    const int tid = threadIdx.x;
    const int b   = blockIdx.x & 7;       // XCD swizzle: batch pinned to XCD
    const int idx = blockIdx.x >> 3;      // 0..191
    const int y   = idx >> 1;
    const int h   = idx & 1;              // x half

    // ---- staging slot (1 per thread; invalid for tid >= 218)
    int w0off = 0;
    const bool v0 = tid < NSEG;
    const float* p0 = in1;                // safe dummy (advances within in1)
    if (v0) p0 = seg_src(tid, b, y, h, in1, in2, &w0off);

    // ---- compute coords (lanes 0..179): dy-major
    const bool isComp = (tid < NCOMP);
    const int  dy = isComp ? (tid / NXG) : 0;
    const int  xg = isComp ? (tid % NXG) : 0;
    const int  x0 = 80 * h + TX * xg;
    const bool rowOk = (y + dy - 4 >= 0) && (y + dy - 4 < H_);
    const bool mzW0 = (h == 0) && (xg == 0);        // words x [-4,0)
    const bool mzW2 = (h == 1) && (xg == NXG - 1);  // words x [160,164)

    const int aof = 16 * xg;                         // in1 words [4xg, 4xg+4)
    const int wof = IN2_OFF + dy * ROW_B + 16 * xg;  // in2 words [4xg-4,4xg+8)

    float acc[ND][TX];
    #pragma unroll
    for (int dx = 0; dx < ND; ++dx)
        #pragma unroll
        for (int j = 0; j < TX; ++j) acc[dx][j] = 0.f;

    // staging register sets (letter-first suffixes: R17 pp-number paste bug)
    float4 SAp0, SAp1;
    float4 SBp0, SBp1;

    #define LOADS(S) do {                                                     \
        S##p0 = *(const float4*)(p0);  S##p1 = *(const float4*)(p0 + HW);     \
        p0 += CHSTEP;                                                         \
    } while (0);

    #define CVTW(BUFI, S) do {                                                \
        if (v0) {                                                             \
            char* base = (char*)lds + (BUFI) * BUF_B;                         \
            *(uint4*)(base + w0off) = make_uint4(                             \
                pk(S##p0.x, S##p1.x), pk(S##p0.y, S##p1.y),                   \
                pk(S##p0.z, S##p1.z), pk(S##p0.w, S##p1.w));                  \
        }                                                                     \
    } while (0);

    #define COMPUTE(BUFI)                                                     \
    if (isComp) {                                                             \
        const char* bb = (const char*)lds + (BUFI) * BUF_B;                   \
        uint4 A0 = *(const uint4*)(bb + aof);                                 \
        uint4 W0 = *(const uint4*)(bb + wof);                                 \
        uint4 W1 = *(const uint4*)(bb + wof + 16);                            \
        uint4 W2 = *(const uint4*)(bb + wof + 32);                            \
        if (mzW0) W0 = make_uint4(0u, 0u, 0u, 0u);                            \
        if (mzW2) W2 = make_uint4(0u, 0u, 0u, 0u);                            \
        unsigned a[4]  = {A0.x, A0.y, A0.z, A0.w};                            \
        unsigned w[12] = {W0.x, W0.y, W0.z, W0.w, W1.x, W1.y, W1.z, W1.w,     \
                          W2.x, W2.y, W2.z, W2.w};                            \
        _Pragma("unroll")                                                     \
        for (int dx = 0; dx < ND; ++dx) {                                     \
            _Pragma("unroll")                                                 \
            for (int j = 0; j < TX; ++j)                                      \
                acc[dx][j] = dot2acc(a[j], w[dx + j], acc[dx][j]);            \
        }                                                                     \
    }

    // body kc (buf kc&3): CVTW chunk kc+2 (regs loaded last body) into buf
    // (kc+2)&3; LOADS kc+3; COMPUTE kc (written 2 bodies + 2 barriers ago);
    // ONE __syncthreads per chunk.
    #define BODY(KM4, SWR, SLD, DOW, DOL)                                     \
        if (DOW) { CVTW(((KM4) + 2) & 3, SWR) }                               \
        if (DOL) { LOADS(SLD) }                                               \
        COMPUTE(KM4)                                                          \
        __syncthreads();

    // ---- prologue: c0->buf0, c1->buf1 (via SA), c2 -> SB regs
    LOADS(SA)          // c0
    CVTW(0, SA)
    LOADS(SA)          // c1
    CVTW(1, SA)
    LOADS(SB)          // c2
    __syncthreads();

    // ---- main loop: kc = 0..123
    #pragma unroll 1
    for (int g = 0; g < 31; ++g) {
        BODY(0, SB, SA, true, true)
        BODY(1, SA, SB, true, true)
        BODY(2, SB, SA, true, true)
        BODY(3, SA, SB, true, true)
    }
    // ---- tail: kc = 124..127
    BODY(0, SB, SA, true, true)    // writes c126, loads c127 -> SA
    BODY(1, SA, SB, true, false)   // writes c127
    BODY(2, SA, SA, false, false)
    BODY(3, SA, SA, false, false)

    #undef BODY
    #undef COMPUTE
    #undef CVTW
    #undef LOADS

    // ---- epilogue: OOB-dy rows output zeros via masked scale
    if (isComp) {
        const float m = rowOk ? (1.0f / (float)C_) : 0.f;
        float* outp = out + ((size_t)(b * NDISP + dy * ND) * H_ + y) * W_ + x0;
        #pragma unroll
        for (int dx = 0; dx < ND; ++dx) {
            float4 o = make_float4(acc[dx][0] * m, acc[dx][1] * m,
                                   acc[dx][2] * m, acc[dx][3] * m);
            *(float4*)(outp + dx * HW) = o;
        }
    }
}

extern "C" void kernel_launch(void* const* d_in, const int* in_sizes, int n_in,
                              void* d_out, int out_size, void* d_ws, size_t ws_size,
                              hipStream_t stream) {
    const float* in1 = (const float*)d_in[0];
    const float* in2 = (const float*)d_in[1];
    float* out = (float*)d_out;

    const int grid = B_ * H_ * 2;   // 1536 blocks (b, y, half) = 6 per CU
    corr_hx16_kernel<<<grid, NTHR, 0, stream>>>(in1, in2, out);
}